// Round 2
// baseline (673.394 us; speedup 1.0000x reference)
//
#include <hip/hip_runtime.h>

#define NTOK 262144
#define TT 64
#define EPS 1e-5f

typedef short short8 __attribute__((ext_vector_type(8)));
typedef float float4v __attribute__((ext_vector_type(4)));

// Packed bf16 weights: [g(4)][nt(16)][kb(8)][lane(64)][j(8)]
// element = W[kb*32 + (lane>>4)*8 + j][nt*16 + (lane&15)]
__device__ __align__(16) short g_Wp[4 * 65536];   // 512 KB static device mem

__device__ __forceinline__ short f2bf(float f) {   // RTN f32->bf16
    uint32_t u = __builtin_bit_cast(uint32_t, f);
    u += 0x7FFFu + ((u >> 16) & 1u);
    return (short)(u >> 16);
}

__global__ void pack_w(const float* __restrict__ W11, const float* __restrict__ W12,
                       const float* __restrict__ W21, const float* __restrict__ W22) {
    int t = blockIdx.x * 256 + threadIdx.x;          // 0 .. 262143
    int g = t >> 16;
    int r = t & 65535;
    int j = r & 7, l = (r >> 3) & 63, kb = (r >> 9) & 7, nt = (r >> 12) & 15;
    int n = nt * 16 + (l & 15);
    int k = kb * 32 + (l >> 4) * 8 + j;
    const float* W = (g == 0) ? W11 : (g == 1) ? W12 : (g == 2) ? W21 : W22;
    g_Wp[t] = f2bf(W[k * 256 + n]);
}

// exact-erf gelu via Abramowitz-Stegun 7.1.26 (max erf err 1.5e-7).
// 1/x via v_rcp_f32 (~1 ulp) — noise vs the poly's own 1.5e-7 error.
__device__ __forceinline__ float gelu_erf(float v) {
    float z = fabsf(v) * 0.70710678118654752f;
    float d = __builtin_fmaf(0.3275911f, z, 1.0f);
    float t;
    asm("v_rcp_f32 %0, %1" : "=v"(t) : "v"(d));
    float poly = t * (0.254829592f + t * (-0.284496736f + t * (1.421413741f
               + t * (-1.453152027f + t * 1.061405429f))));
    float er = 1.0f - poly * __expf(-z * z);
    er = copysignf(er, v);
    return 0.5f * v * (1.0f + er);
}

// A-operand packed LDS index for element (m, k), with rotr2 lane-slot swizzle.
// Frag-lane l' = (m&15) | (((k>>3)&3)<<4); stored 16B-unit slot = g(l') where
// g(l') = (l'>>2) | ((l'&3)<<4)  (bijection on 0..63).
// This makes the LN/GELU ds_write_b16 pattern bank-conflict-free:
// bank = 16*(c>>3) + 4q + ((c&7)>>1)  -> 2 lanes/bank (free, m136).
// Reads use slot g(lane): any permutation of 16B units is conflict-free.
// B (g_Wp) is untouched — only A's LDS placement moves, operands unchanged.
__device__ __forceinline__ int aidx(int m, int k) {
    int lp = (m & 15) | (((k >> 3) & 3) << 4);
    int gs = (lp >> 2) | ((lp & 3) << 4);
    return ((((m >> 4) * 8 + (k >> 5)) * 64) + gs) * 8 + (k & 7);
}

// NOTE: __launch_bounds__(256,1). (256,2) caps unified VGPR+AGPR at 256 and
// produced wrong results in earlier rounds (register-pressure codegen); with
// (256,1) the allocator has headroom and HW occupancy is still 2 blocks/CU
// (LDS: 80 KB/block -> exactly 2 of 160 KB).
__global__ __launch_bounds__(256, 1) void fused_kernel(
    const float* __restrict__ meas, const float* __restrict__ event,
    const float* __restrict__ leak, const float* __restrict__ elk,
    const int* __restrict__ sids, const int* __restrict__ cids,
    const float* __restrict__ w_meas, const float* __restrict__ w_event,
    const float* __restrict__ w_leak, const float* __restrict__ w_el,
    const float* __restrict__ b_meas, const float* __restrict__ b_event,
    const float* __restrict__ b_leak, const float* __restrict__ b_el,
    const float* __restrict__ stab_table, const float* __restrict__ cycle_table,
    const float* __restrict__ g1, const float* __restrict__ be1,
    const float* __restrict__ b11, const float* __restrict__ b12,
    const float* __restrict__ g2, const float* __restrict__ be2,
    const float* __restrict__ b21, const float* __restrict__ b22,
    float* __restrict__ out)
{
    // Double-buffered A tiles (removes GELU-entry barriers): 2 x 32 KB
    __shared__ __align__(16) short Abuf[2][4 * 8 * 64 * 8];
    __shared__ float par[13 * 256];                       // 13 KB staged params
    // overlay union (3 KB): embed phase uses rowf[4][64]+rowi[2][64];
    // LN phases reuse it as redp[64][12] (a[4] | b[4] | pad[4], 48B stride so
    // the per-q b128 stat reads land on distinct banks, 16B-aligned rows)
    __shared__ __align__(16) float ubuf[768];

    float (*rowf)[TT] = (float (*)[TT])ubuf;              // [4][64]
    int   (*rowi)[TT] = (int (*)[TT])(ubuf + 256);        // [2][64]
    float *redp = ubuf;                                   // [64][12]

    const int tid = threadIdx.x;
    const int w = tid >> 6, lane = tid & 63;
    const int q = lane >> 4, c = lane & 15;
    const int gl = (lane >> 2) | ((lane & 3) << 4);       // g(lane): A read slot
    const int R0 = blockIdx.x * TT;

    {   // stage per-feature params (one column per thread)
        int n = tid;
        par[0 * 256 + n] = w_meas[n];
        par[1 * 256 + n] = w_event[n];
        par[2 * 256 + n] = w_leak[n];
        par[3 * 256 + n] = w_el[n];
        par[4 * 256 + n] = b_meas[n] + b_event[n] + b_leak[n] + b_el[n];
        par[5 * 256 + n] = g1[n];
        par[6 * 256 + n] = be1[n];
        par[7 * 256 + n] = b11[n];
        par[8 * 256 + n] = b12[n];
        par[9 * 256 + n] = g2[n];
        par[10 * 256 + n] = be2[n];
        par[11 * 256 + n] = b21[n];
        par[12 * 256 + n] = b22[n];
    }
    if (tid < TT) {
        rowf[0][tid] = meas[R0 + tid];
        rowf[1][tid] = event[R0 + tid];
        rowf[2][tid] = leak[R0 + tid];
        rowf[3][tid] = elk[R0 + tid];
        rowi[0][tid] = sids[R0 + tid];
        rowi[1][tid] = cids[R0 + tid];
    }
    __syncthreads();

    // residual x in MFMA C-layout registers: [rg][ntl][reg]
    // element: row m = rg*16 + 4*q + reg, col n = w*64 + ntl*16 + c
    float xr[4][4][4];
    #pragma unroll
    for (int rg = 0; rg < 4; ++rg)
        #pragma unroll
        for (int reg = 0; reg < 4; ++reg) {
            int m = rg * 16 + 4 * q + reg;
            float mv = rowf[0][m], ev = rowf[1][m], lv = rowf[2][m], e2 = rowf[3][m];
            const float* srow = stab_table + rowi[0][m] * 256;
            const float* crow = cycle_table + rowi[1][m] * 256;
            #pragma unroll
            for (int ntl = 0; ntl < 4; ++ntl) {
                int n = w * 64 + ntl * 16 + c;
                xr[rg][ntl][reg] = mv * par[n] + ev * par[256 + n] + lv * par[512 + n]
                                 + e2 * par[768 + n] + par[1024 + n] + srow[n] + crow[n];
            }
        }
    __syncthreads();   // rowf/rowi reads done before redp overlay writes

    float4v acc[4][4];

    // LN part 1: per-wave partial sums -> redp (c==0 lanes). Caller barriers.
    auto ln_reduce = [&]() {
        float s[4][4], s2[4][4];
        #pragma unroll
        for (int rg = 0; rg < 4; ++rg)
            #pragma unroll
            for (int reg = 0; reg < 4; ++reg) {
                float a = 0.f, b = 0.f;
                #pragma unroll
                for (int ntl = 0; ntl < 4; ++ntl) {
                    float v = xr[rg][ntl][reg];
                    a += v; b += v * v;
                }
                #pragma unroll
                for (int d = 1; d < 16; d <<= 1) {
                    a += __shfl_xor(a, d, 64);
                    b += __shfl_xor(b, d, 64);
                }
                s[rg][reg] = a; s2[rg][reg] = b;
            }
        if (c == 0) {
            #pragma unroll
            for (int rg = 0; rg < 4; ++rg)
                #pragma unroll
                for (int reg = 0; reg < 4; ++reg) {
                    int m = rg * 16 + 4 * q + reg;
                    redp[m * 12 + w] = s[rg][reg];
                    redp[m * 12 + 4 + w] = s2[rg][reg];
                }
        }
    };

    // LN part 2: every thread derives mu/rsigma from redp (2 broadcast b128
    // reads per row — no tid<64 serial phase, no extra barrier), writes A.
    auto ln_write = [&](const float* g, const float* be, short* A) {
        float gv[4], bv[4];
        #pragma unroll
        for (int ntl = 0; ntl < 4; ++ntl) {
            int n = w * 64 + ntl * 16 + c;
            gv[ntl] = g[n]; bv[ntl] = be[n];
        }
        #pragma unroll
        for (int rg = 0; rg < 4; ++rg)
            #pragma unroll
            for (int reg = 0; reg < 4; ++reg) {
                int m = rg * 16 + 4 * q + reg;
                float4v a4 = *(const float4v*)&redp[m * 12];
                float4v b4 = *(const float4v*)&redp[m * 12 + 4];
                float a = a4[0] + a4[1] + a4[2] + a4[3];
                float b = b4[0] + b4[1] + b4[2] + b4[3];
                float mu = a * (1.0f / 256.0f);
                float ve = b * (1.0f / 256.0f) - mu * mu + EPS;
                float rs;
                asm("v_rsq_f32 %0, %1" : "=v"(rs) : "v"(ve));
                #pragma unroll
                for (int ntl = 0; ntl < 4; ++ntl) {
                    int n = w * 64 + ntl * 16 + c;
                    A[aidx(m, n)] = f2bf((xr[rg][ntl][reg] - mu) * rs * gv[ntl] + bv[ntl]);
                }
            }
    };

    // Issue gemm g's kb=0 B-fragments early: pure global(L2) loads with no LDS
    // dependence — latency hides under the A-write phase + barrier wait.
    auto preB = [&](int g4, short8 bh0[4]) {
        const short* W = g_Wp + g4 * 65536;
        #pragma unroll
        for (int ntl = 0; ntl < 4; ++ntl) {
            int nt = w * 4 + ntl;
            bh0[ntl] = *(const short8*)&W[((nt * 8 + 0) * 64 + lane) * 8];
        }
    };

    // Ping-pong software pipeline: kb+1 fragments (LDS A + global B) issued
    // before kb's MFMAs so load latency overlaps the 16-MFMA cluster.
    // T5: s_setprio(1) around each MFMA cluster — with 2 independent
    // blocks/CU at different phases, the MFMA-phase wave wins issue
    // arbitration over the co-resident block's VALU/store waves.
    auto do_gemm = [&](int g4, const short* A, const short8 bh0[4]) {
        const short* W = g_Wp + g4 * 65536;
        #pragma unroll
        for (int rg = 0; rg < 4; ++rg)
            #pragma unroll
            for (int ntl = 0; ntl < 4; ++ntl)
                acc[rg][ntl] = (float4v){0.f, 0.f, 0.f, 0.f};
        short8 ah[2][4], bh[2][4];
        #pragma unroll
        for (int rg = 0; rg < 4; ++rg)
            ah[0][rg] = *(const short8*)&A[((rg * 8 + 0) * 64 + gl) * 8];
        #pragma unroll
        for (int ntl = 0; ntl < 4; ++ntl)
            bh[0][ntl] = bh0[ntl];
        #pragma unroll
        for (int kb = 0; kb < 8; ++kb) {
            const int cur = kb & 1, nxt = cur ^ 1;
            if (kb < 7) {
                #pragma unroll
                for (int rg = 0; rg < 4; ++rg)
                    ah[nxt][rg] = *(const short8*)&A[((rg * 8 + kb + 1) * 64 + gl) * 8];
                #pragma unroll
                for (int ntl = 0; ntl < 4; ++ntl) {
                    int nt = w * 4 + ntl;
                    bh[nxt][ntl] = *(const short8*)&W[((nt * 8 + kb + 1) * 64 + lane) * 8];
                }
            }
            __builtin_amdgcn_s_setprio(1);
            #pragma unroll
            for (int rg = 0; rg < 4; ++rg)
                #pragma unroll
                for (int ntl = 0; ntl < 4; ++ntl)
                    acc[rg][ntl] = __builtin_amdgcn_mfma_f32_16x16x32_bf16(
                        ah[cur][rg], bh[cur][ntl], acc[rg][ntl], 0, 0, 0);
            __builtin_amdgcn_s_setprio(0);
        }
    };

    // No entry barrier: writes go to the OTHER A buffer than the one just read.
    auto gelu_write = [&](const float* bias, short* A) {
        float bv[4];
        #pragma unroll
        for (int ntl = 0; ntl < 4; ++ntl)
            bv[ntl] = bias[w * 64 + ntl * 16 + c];
        #pragma unroll
        for (int rg = 0; rg < 4; ++rg)
            #pragma unroll
            for (int ntl = 0; ntl < 4; ++ntl)
                #pragma unroll
                for (int reg = 0; reg < 4; ++reg) {
                    int m = rg * 16 + 4 * q + reg;
                    int n = w * 64 + ntl * 16 + c;
                    A[aidx(m, n)] = f2bf(gelu_erf(acc[rg][ntl][reg] + bv[ntl]));
                }
    };

    short* A0 = Abuf[0];
    short* A1 = Abuf[1];
    short8 bh0[4];

    // ---- res block 1 ----  (8 barriers total per block vs previous 12)
    ln_reduce();
    __syncthreads();                       // redp visible
    preB(0, bh0);
    ln_write(par + 5 * 256, par + 6 * 256, A0);
    __syncthreads();                       // A0 ready
    do_gemm(0, A0, bh0);
    preB(1, bh0);
    gelu_write(par + 7 * 256, A1);
    __syncthreads();                       // A1 ready
    do_gemm(1, A1, bh0);
    {
        float bv[4];
        #pragma unroll
        for (int ntl = 0; ntl < 4; ++ntl)
            bv[ntl] = par[8 * 256 + w * 64 + ntl * 16 + c];
        #pragma unroll
        for (int rg = 0; rg < 4; ++rg)
            #pragma unroll
            for (int ntl = 0; ntl < 4; ++ntl)
                #pragma unroll
                for (int reg = 0; reg < 4; ++reg)
                    xr[rg][ntl][reg] += acc[rg][ntl][reg] + bv[ntl];
    }

    // ---- res block 2 ----
    ln_reduce();                           // redp last read pre-gemm0 barrier: safe
    __syncthreads();                       // redp visible
    preB(2, bh0);
    ln_write(par + 9 * 256, par + 10 * 256, A0);   // all waves past gemm0: safe
    __syncthreads();                       // A0 ready
    do_gemm(2, A0, bh0);
    preB(3, bh0);
    gelu_write(par + 11 * 256, A1);        // all waves past gemm1: safe
    __syncthreads();                       // A1 ready
    do_gemm(3, A1, bh0);

    // ---- epilogue: out = x + C4 + b22 ----
    {
        float bv[4];
        #pragma unroll
        for (int ntl = 0; ntl < 4; ++ntl)
            bv[ntl] = par[12 * 256 + w * 64 + ntl * 16 + c];
        #pragma unroll
        for (int rg = 0; rg < 4; ++rg)
            #pragma unroll
            for (int ntl = 0; ntl < 4; ++ntl)
                #pragma unroll
                for (int reg = 0; reg < 4; ++reg) {
                    int m = rg * 16 + 4 * q + reg;
                    int n = w * 64 + ntl * 16 + c;
                    out[(size_t)(R0 + m) * 256 + n] =
                        xr[rg][ntl][reg] + acc[rg][ntl][reg] + bv[ntl];
                }
    }
}

extern "C" void kernel_launch(void* const* d_in, const int* in_sizes, int n_in,
                              void* d_out, int out_size, void* d_ws, size_t ws_size,
                              hipStream_t stream) {
    pack_w<<<1024, 256, 0, stream>>>(
        (const float*)d_in[18], (const float*)d_in[20],
        (const float*)d_in[24], (const float*)d_in[26]);
    fused_kernel<<<NTOK / TT, 256, 0, stream>>>(
        (const float*)d_in[0], (const float*)d_in[1],
        (const float*)d_in[2], (const float*)d_in[3],
        (const int*)d_in[4], (const int*)d_in[5],
        (const float*)d_in[6], (const float*)d_in[8],
        (const float*)d_in[10], (const float*)d_in[12],
        (const float*)d_in[7], (const float*)d_in[9],
        (const float*)d_in[11], (const float*)d_in[13],
        (const float*)d_in[14], (const float*)d_in[15],
        (const float*)d_in[16], (const float*)d_in[17],
        (const float*)d_in[19], (const float*)d_in[21],
        (const float*)d_in[22], (const float*)d_in[23],
        (const float*)d_in[25], (const float*)d_in[27],
        (float*)d_out);
}

// Round 3
// 671.137 us; speedup vs baseline: 1.0034x; 1.0034x over previous
//
#include <hip/hip_runtime.h>

#define NTOK 262144
#define TT 64
#define EPS 1e-5f

typedef short short8 __attribute__((ext_vector_type(8)));
typedef float float4v __attribute__((ext_vector_type(4)));

// Packed bf16 weights: [g(4)][nt(16)][kb(8)][lane(64)][j(8)]
// element = W[kb*32 + (lane>>4)*8 + j][nt*16 + (lane&15)]
__device__ __align__(16) short g_Wp[4 * 65536];   // 512 KB static device mem

__device__ __forceinline__ short f2bf(float f) {   // RTN f32->bf16
    uint32_t u = __builtin_bit_cast(uint32_t, f);
    u += 0x7FFFu + ((u >> 16) & 1u);
    return (short)(u >> 16);
}

__global__ void pack_w(const float* __restrict__ W11, const float* __restrict__ W12,
                       const float* __restrict__ W21, const float* __restrict__ W22) {
    int t = blockIdx.x * 256 + threadIdx.x;          // 0 .. 262143
    int g = t >> 16;
    int r = t & 65535;
    int j = r & 7, l = (r >> 3) & 63, kb = (r >> 9) & 7, nt = (r >> 12) & 15;
    int n = nt * 16 + (l & 15);
    int k = kb * 32 + (l >> 4) * 8 + j;
    const float* W = (g == 0) ? W11 : (g == 1) ? W12 : (g == 2) ? W21 : W22;
    g_Wp[t] = f2bf(W[k * 256 + n]);
}

// exact-erf gelu via Abramowitz-Stegun 7.1.26 (max erf err 1.5e-7).
// 1/x via v_rcp_f32 (~1 ulp) — noise vs the poly's own 1.5e-7 error.
__device__ __forceinline__ float gelu_erf(float v) {
    float z = fabsf(v) * 0.70710678118654752f;
    float d = __builtin_fmaf(0.3275911f, z, 1.0f);
    float t;
    asm("v_rcp_f32 %0, %1" : "=v"(t) : "v"(d));
    float poly = t * (0.254829592f + t * (-0.284496736f + t * (1.421413741f
               + t * (-1.453152027f + t * 1.061405429f))));
    float er = 1.0f - poly * __expf(-z * z);
    er = copysignf(er, v);
    return 0.5f * v * (1.0f + er);
}

// A-operand packed LDS index for element (m, k), with rotr2 lane-slot swizzle.
// Frag-lane l' = (m&15) | (((k>>3)&3)<<4); stored 16B-unit slot = g(l') where
// g(l') = (l'>>2) | ((l'&3)<<4)  (bijection on 0..63).
// LN/GELU ds_write_b16 bank = 4q + 16*(c>>3) + ((c&7)>>1): 2 lanes/bank (free).
// Reads use slot g(lane): any permutation of 16B units is conflict-free.
__device__ __forceinline__ int aidx(int m, int k) {
    int lp = (m & 15) | (((k >> 3) & 3) << 4);
    int gs = (lp >> 2) | ((lp & 3) << 4);
    return ((((m >> 4) * 8 + (k >> 5)) * 64) + gs) * 8 + (k & 7);
}

// NOTE: __launch_bounds__(256,1). (256,2) caps unified VGPR+AGPR at 256 and
// produced wrong results in earlier rounds (register-pressure codegen); with
// (256,1) the allocator lands at ~164 VGPR which still permits 3 waves/SIMD
// (512/164 = 3.12). LDS is now the binding limit: 48 KB/block -> 3 blocks/CU
// (144 of 160 KB). VGPR must stay <= 170 for this to hold — check
// kernel-resource-usage if perf regresses.
__global__ __launch_bounds__(256, 1) void fused_kernel(
    const float* __restrict__ meas, const float* __restrict__ event,
    const float* __restrict__ leak, const float* __restrict__ elk,
    const int* __restrict__ sids, const int* __restrict__ cids,
    const float* __restrict__ w_meas, const float* __restrict__ w_event,
    const float* __restrict__ w_leak, const float* __restrict__ w_el,
    const float* __restrict__ b_meas, const float* __restrict__ b_event,
    const float* __restrict__ b_leak, const float* __restrict__ b_el,
    const float* __restrict__ stab_table, const float* __restrict__ cycle_table,
    const float* __restrict__ g1, const float* __restrict__ be1,
    const float* __restrict__ b11, const float* __restrict__ b12,
    const float* __restrict__ g2, const float* __restrict__ be2,
    const float* __restrict__ b21, const float* __restrict__ b22,
    float* __restrict__ out)
{
    // Single A tile (32 KB) — 48 KB total LDS -> 3 blocks/CU for TLP.
    __shared__ __align__(16) short Abuf[4 * 8 * 64 * 8];
    __shared__ float par[13 * 256];                       // 13 KB staged params
    // overlay union (3 KB): embed phase uses rowf[4][64]+rowi[2][64];
    // LN phases reuse it as redp[64][12] (a[4] | b[4] | pad[4], 48B stride)
    __shared__ __align__(16) float ubuf[768];

    float (*rowf)[TT] = (float (*)[TT])ubuf;              // [4][64]
    int   (*rowi)[TT] = (int (*)[TT])(ubuf + 256);        // [2][64]
    float *redp = ubuf;                                   // [64][12]

    const int tid = threadIdx.x;
    const int w = tid >> 6, lane = tid & 63;
    const int q = lane >> 4, c = lane & 15;
    const int gl = (lane >> 2) | ((lane & 3) << 4);       // g(lane): A read slot
    const int R0 = blockIdx.x * TT;

    {   // stage per-feature params (one column per thread)
        int n = tid;
        par[0 * 256 + n] = w_meas[n];
        par[1 * 256 + n] = w_event[n];
        par[2 * 256 + n] = w_leak[n];
        par[3 * 256 + n] = w_el[n];
        par[4 * 256 + n] = b_meas[n] + b_event[n] + b_leak[n] + b_el[n];
        par[5 * 256 + n] = g1[n];
        par[6 * 256 + n] = be1[n];
        par[7 * 256 + n] = b11[n];
        par[8 * 256 + n] = b12[n];
        par[9 * 256 + n] = g2[n];
        par[10 * 256 + n] = be2[n];
        par[11 * 256 + n] = b21[n];
        par[12 * 256 + n] = b22[n];
    }
    if (tid < TT) {
        rowf[0][tid] = meas[R0 + tid];
        rowf[1][tid] = event[R0 + tid];
        rowf[2][tid] = leak[R0 + tid];
        rowf[3][tid] = elk[R0 + tid];
        rowi[0][tid] = sids[R0 + tid];
        rowi[1][tid] = cids[R0 + tid];
    }
    __syncthreads();

    // residual x in MFMA C-layout registers: [rg][ntl][reg]
    // element: row m = rg*16 + 4*q + reg, col n = w*64 + ntl*16 + c
    float xr[4][4][4];
    #pragma unroll
    for (int rg = 0; rg < 4; ++rg)
        #pragma unroll
        for (int reg = 0; reg < 4; ++reg) {
            int m = rg * 16 + 4 * q + reg;
            float mv = rowf[0][m], ev = rowf[1][m], lv = rowf[2][m], e2 = rowf[3][m];
            const float* srow = stab_table + rowi[0][m] * 256;
            const float* crow = cycle_table + rowi[1][m] * 256;
            #pragma unroll
            for (int ntl = 0; ntl < 4; ++ntl) {
                int n = w * 64 + ntl * 16 + c;
                xr[rg][ntl][reg] = mv * par[n] + ev * par[256 + n] + lv * par[512 + n]
                                 + e2 * par[768 + n] + par[1024 + n] + srow[n] + crow[n];
            }
        }
    __syncthreads();   // rowf/rowi reads done before redp overlay writes

    float4v acc[4][4];

    // LN part 1: per-wave partial sums -> redp (c==0 lanes). Caller barriers.
    auto ln_reduce = [&]() {
        float s[4][4], s2[4][4];
        #pragma unroll
        for (int rg = 0; rg < 4; ++rg)
            #pragma unroll
            for (int reg = 0; reg < 4; ++reg) {
                float a = 0.f, b = 0.f;
                #pragma unroll
                for (int ntl = 0; ntl < 4; ++ntl) {
                    float v = xr[rg][ntl][reg];
                    a += v; b += v * v;
                }
                #pragma unroll
                for (int d = 1; d < 16; d <<= 1) {
                    a += __shfl_xor(a, d, 64);
                    b += __shfl_xor(b, d, 64);
                }
                s[rg][reg] = a; s2[rg][reg] = b;
            }
        if (c == 0) {
            #pragma unroll
            for (int rg = 0; rg < 4; ++rg)
                #pragma unroll
                for (int reg = 0; reg < 4; ++reg) {
                    int m = rg * 16 + 4 * q + reg;
                    redp[m * 12 + w] = s[rg][reg];
                    redp[m * 12 + 4 + w] = s2[rg][reg];
                }
        }
    };

    // LN part 2: every thread derives mu/rsigma from redp (2 broadcast b128
    // reads per row — no tid<64 serial phase, no extra barrier), writes A.
    auto ln_write = [&](const float* g, const float* be, short* A) {
        float gv[4], bv[4];
        #pragma unroll
        for (int ntl = 0; ntl < 4; ++ntl) {
            int n = w * 64 + ntl * 16 + c;
            gv[ntl] = g[n]; bv[ntl] = be[n];
        }
        #pragma unroll
        for (int rg = 0; rg < 4; ++rg)
            #pragma unroll
            for (int reg = 0; reg < 4; ++reg) {
                int m = rg * 16 + 4 * q + reg;
                float4v a4 = *(const float4v*)&redp[m * 12];
                float4v b4 = *(const float4v*)&redp[m * 12 + 4];
                float a = a4[0] + a4[1] + a4[2] + a4[3];
                float b = b4[0] + b4[1] + b4[2] + b4[3];
                float mu = a * (1.0f / 256.0f);
                float ve = b * (1.0f / 256.0f) - mu * mu + EPS;
                float rs;
                asm("v_rsq_f32 %0, %1" : "=v"(rs) : "v"(ve));
                #pragma unroll
                for (int ntl = 0; ntl < 4; ++ntl) {
                    int n = w * 64 + ntl * 16 + c;
                    A[aidx(m, n)] = f2bf((xr[rg][ntl][reg] - mu) * rs * gv[ntl] + bv[ntl]);
                }
            }
    };

    // Issue gemm g's kb=0 B-fragments early: pure global(L2) loads with no LDS
    // dependence — latency hides under the A-write phase + barrier wait.
    auto preB = [&](int g4, short8 bh0[4]) {
        const short* W = g_Wp + g4 * 65536;
        #pragma unroll
        for (int ntl = 0; ntl < 4; ++ntl) {
            int nt = w * 4 + ntl;
            bh0[ntl] = *(const short8*)&W[((nt * 8 + 0) * 64 + lane) * 8];
        }
    };

    // Ping-pong software pipeline: kb+1 fragments (LDS A + global B) issued
    // before kb's MFMAs so load latency overlaps the 16-MFMA cluster.
    // T5: s_setprio(1) around each MFMA cluster — with 3 phase-staggered
    // blocks/CU, the MFMA-phase wave wins issue arbitration over the
    // co-resident blocks' VALU/store waves.
    auto do_gemm = [&](int g4, const short* A, const short8 bh0[4]) {
        const short* W = g_Wp + g4 * 65536;
        #pragma unroll
        for (int rg = 0; rg < 4; ++rg)
            #pragma unroll
            for (int ntl = 0; ntl < 4; ++ntl)
                acc[rg][ntl] = (float4v){0.f, 0.f, 0.f, 0.f};
        short8 ah[2][4], bh[2][4];
        #pragma unroll
        for (int rg = 0; rg < 4; ++rg)
            ah[0][rg] = *(const short8*)&A[((rg * 8 + 0) * 64 + gl) * 8];
        #pragma unroll
        for (int ntl = 0; ntl < 4; ++ntl)
            bh[0][ntl] = bh0[ntl];
        #pragma unroll
        for (int kb = 0; kb < 8; ++kb) {
            const int cur = kb & 1, nxt = cur ^ 1;
            if (kb < 7) {
                #pragma unroll
                for (int rg = 0; rg < 4; ++rg)
                    ah[nxt][rg] = *(const short8*)&A[((rg * 8 + kb + 1) * 64 + gl) * 8];
                #pragma unroll
                for (int ntl = 0; ntl < 4; ++ntl) {
                    int nt = w * 4 + ntl;
                    bh[nxt][ntl] = *(const short8*)&W[((nt * 8 + kb + 1) * 64 + lane) * 8];
                }
            }
            __builtin_amdgcn_s_setprio(1);
            #pragma unroll
            for (int rg = 0; rg < 4; ++rg)
                #pragma unroll
                for (int ntl = 0; ntl < 4; ++ntl)
                    acc[rg][ntl] = __builtin_amdgcn_mfma_f32_16x16x32_bf16(
                        ah[cur][rg], bh[cur][ntl], acc[rg][ntl], 0, 0, 0);
            __builtin_amdgcn_s_setprio(0);
        }
    };

    auto gelu_write = [&](const float* bias, short* A) {
        float bv[4];
        #pragma unroll
        for (int ntl = 0; ntl < 4; ++ntl)
            bv[ntl] = bias[w * 64 + ntl * 16 + c];
        #pragma unroll
        for (int rg = 0; rg < 4; ++rg)
            #pragma unroll
            for (int ntl = 0; ntl < 4; ++ntl)
                #pragma unroll
                for (int reg = 0; reg < 4; ++reg) {
                    int m = rg * 16 + 4 * q + reg;
                    int n = w * 64 + ntl * 16 + c;
                    A[aidx(m, n)] = f2bf(gelu_erf(acc[rg][ntl][reg] + bv[ntl]));
                }
    };

    short* A = Abuf;
    short8 bh0[4];

    // ---- res block 1 ---- (single A buffer: writers barrier against readers)
    ln_reduce();
    __syncthreads();                       // redp visible
    preB(0, bh0);
    ln_write(par + 5 * 256, par + 6 * 256, A);
    __syncthreads();                       // A ready
    do_gemm(0, A, bh0);
    preB(1, bh0);
    __syncthreads();                       // all waves done reading A (gemm0)
    gelu_write(par + 7 * 256, A);
    __syncthreads();                       // A ready
    do_gemm(1, A, bh0);
    {
        float bv[4];
        #pragma unroll
        for (int ntl = 0; ntl < 4; ++ntl)
            bv[ntl] = par[8 * 256 + w * 64 + ntl * 16 + c];
        #pragma unroll
        for (int rg = 0; rg < 4; ++rg)
            #pragma unroll
            for (int ntl = 0; ntl < 4; ++ntl)
                #pragma unroll
                for (int reg = 0; reg < 4; ++reg)
                    xr[rg][ntl][reg] += acc[rg][ntl][reg] + bv[ntl];
    }

    // ---- res block 2 ----
    ln_reduce();                           // redp last read before gemm0: safe
    __syncthreads();                       // redp visible + all waves past gemm1
    preB(2, bh0);
    ln_write(par + 9 * 256, par + 10 * 256, A);
    __syncthreads();                       // A ready
    do_gemm(2, A, bh0);
    preB(3, bh0);
    __syncthreads();                       // all waves done reading A (gemm2)
    gelu_write(par + 11 * 256, A);
    __syncthreads();                       // A ready
    do_gemm(3, A, bh0);

    // ---- epilogue: out = x + C4 + b22 ----
    {
        float bv[4];
        #pragma unroll
        for (int ntl = 0; ntl < 4; ++ntl)
            bv[ntl] = par[12 * 256 + w * 64 + ntl * 16 + c];
        #pragma unroll
        for (int rg = 0; rg < 4; ++rg)
            #pragma unroll
            for (int ntl = 0; ntl < 4; ++ntl)
                #pragma unroll
                for (int reg = 0; reg < 4; ++reg) {
                    int m = rg * 16 + 4 * q + reg;
                    int n = w * 64 + ntl * 16 + c;
                    out[(size_t)(R0 + m) * 256 + n] =
                        xr[rg][ntl][reg] + acc[rg][ntl][reg] + bv[ntl];
                }
    }
}

extern "C" void kernel_launch(void* const* d_in, const int* in_sizes, int n_in,
                              void* d_out, int out_size, void* d_ws, size_t ws_size,
                              hipStream_t stream) {
    pack_w<<<1024, 256, 0, stream>>>(
        (const float*)d_in[18], (const float*)d_in[20],
        (const float*)d_in[24], (const float*)d_in[26]);
    fused_kernel<<<NTOK / TT, 256, 0, stream>>>(
        (const float*)d_in[0], (const float*)d_in[1],
        (const float*)d_in[2], (const float*)d_in[3],
        (const int*)d_in[4], (const int*)d_in[5],
        (const float*)d_in[6], (const float*)d_in[8],
        (const float*)d_in[10], (const float*)d_in[12],
        (const float*)d_in[7], (const float*)d_in[9],
        (const float*)d_in[11], (const float*)d_in[13],
        (const float*)d_in[14], (const float*)d_in[15],
        (const float*)d_in[16], (const float*)d_in[17],
        (const float*)d_in[19], (const float*)d_in[21],
        (const float*)d_in[22], (const float*)d_in[23],
        (const float*)d_in[25], (const float*)d_in[27],
        (float*)d_out);
}

// Round 5
// 608.518 us; speedup vs baseline: 1.1066x; 1.1029x over previous
//
#include <hip/hip_runtime.h>

#define NTOK 262144
#define TT 64
#define EPS 1e-5f

typedef short short8 __attribute__((ext_vector_type(8)));
typedef float float4v __attribute__((ext_vector_type(4)));

// Packed bf16 weights: [g(4)][nt(16)][kb(8)][lane(64)][j(8)]
// element = W[kb*32 + (lane>>4)*8 + j][nt*16 + (lane&15)]
__device__ __align__(16) short g_Wp[4 * 65536];   // 512 KB static device mem

__device__ __forceinline__ short f2bf(float f) {   // RTN f32->bf16
    uint32_t u = __builtin_bit_cast(uint32_t, f);
    u += 0x7FFFu + ((u >> 16) & 1u);
    return (short)(u >> 16);
}

__global__ void pack_w(const float* __restrict__ W11, const float* __restrict__ W12,
                       const float* __restrict__ W21, const float* __restrict__ W22) {
    int t = blockIdx.x * 256 + threadIdx.x;          // 0 .. 262143
    int g = t >> 16;
    int r = t & 65535;
    int j = r & 7, l = (r >> 3) & 63, kb = (r >> 9) & 7, nt = (r >> 12) & 15;
    int n = nt * 16 + (l & 15);
    int k = kb * 32 + (l >> 4) * 8 + j;
    const float* W = (g == 0) ? W11 : (g == 1) ? W12 : (g == 2) ? W21 : W22;
    g_Wp[t] = f2bf(W[k * 256 + n]);
}

// exact-erf gelu via Abramowitz-Stegun 7.1.26 (max erf err 1.5e-7).
__device__ __forceinline__ float gelu_erf(float v) {
    float z = fabsf(v) * 0.70710678118654752f;
    float d = __builtin_fmaf(0.3275911f, z, 1.0f);
    float t;
    asm("v_rcp_f32 %0, %1" : "=v"(t) : "v"(d));
    float poly = t * (0.254829592f + t * (-0.284496736f + t * (1.421413741f
               + t * (-1.453152027f + t * 1.061405429f))));
    float er = 1.0f - poly * __expf(-z * z);
    er = copysignf(er, v);
    return 0.5f * v * (1.0f + er);
}

// A-operand packed LDS index for element (m, k), rotr2 lane-slot swizzle.
// ds_write_b16 bank = 4q + 16*(c>>3) + ((c&7)>>1): 2 lanes/bank (free, m136).
__device__ __forceinline__ int aidx(int m, int k) {
    int lp = (m & 15) | (((k >> 3) & 3) << 4);
    int gs = (lp >> 2) | ((lp & 3) << 4);
    return ((((m >> 4) * 8 + (k >> 5)) * 64) + gs) * 8 + (k & 7);
}

// Dual-tile anti-phase pipeline: 512 threads = 2 x (4 waves, 64 tokens).
// Tile B runs one sub-phase behind tile A so every GEMM sub-phase of one
// tile overlaps a VALU sub-phase (LN/GELU/res/store) of the other on the
// same SIMDs (MFMA and VALU are separate pipes). 83 KB LDS -> 1 block/CU,
// 8 waves resident, overlap guaranteed within the block.
// VGPR cap for 512-thr blocks is 256 (2 waves/SIMD); we use ~165.
__global__ __launch_bounds__(512, 1) void fused_kernel(
    const float* __restrict__ meas, const float* __restrict__ event,
    const float* __restrict__ leak, const float* __restrict__ elk,
    const int* __restrict__ sids, const int* __restrict__ cids,
    const float* __restrict__ w_meas, const float* __restrict__ w_event,
    const float* __restrict__ w_leak, const float* __restrict__ w_el,
    const float* __restrict__ b_meas, const float* __restrict__ b_event,
    const float* __restrict__ b_leak, const float* __restrict__ b_el,
    const float* __restrict__ stab_table, const float* __restrict__ cycle_table,
    const float* __restrict__ g1, const float* __restrict__ be1,
    const float* __restrict__ b11, const float* __restrict__ b12,
    const float* __restrict__ g2, const float* __restrict__ be2,
    const float* __restrict__ b21, const float* __restrict__ b22,
    float* __restrict__ out)
{
    __shared__ __align__(16) short Abuf[2][4 * 8 * 64 * 8];  // 2 x 32 KB (per tile)
    __shared__ float par[13 * 256];                          // 13 KB shared params
    __shared__ __align__(16) float ubuf[2][768];             // per-tile overlay

    const int tid = threadIdx.x;
    const int w = tid >> 6;                 // 0..7
    const int half = w >> 2;                // tile id: 0 = waves 0-3, 1 = waves 4-7
    const int wh = w & 3;                   // wave-in-tile
    const int lane = tid & 63;
    const int q = lane >> 4, c = lane & 15;
    const int gl = (lane >> 2) | ((lane & 3) << 4);   // A read slot
    const int R0h = blockIdx.x * 2 * TT + half * TT;  // this tile's token base

    float (*rowf)[TT] = (float (*)[TT])ubuf[half];           // [4][64]
    int   (*rowi)[TT] = (int (*)[TT])(ubuf[half] + 256);     // [2][64]
    float *redp = ubuf[half];                                // [64][12]
    short *Ah = Abuf[half];

    // ---- s1: stage ----
    if (tid < 256) {
        int n = tid;
        par[0 * 256 + n] = w_meas[n];
        par[1 * 256 + n] = w_event[n];
        par[2 * 256 + n] = w_leak[n];
        par[3 * 256 + n] = w_el[n];
        par[4 * 256 + n] = b_meas[n] + b_event[n] + b_leak[n] + b_el[n];
        par[5 * 256 + n] = g1[n];
        par[6 * 256 + n] = be1[n];
        par[7 * 256 + n] = b11[n];
        par[8 * 256 + n] = b12[n];
        par[9 * 256 + n] = g2[n];
        par[10 * 256 + n] = be2[n];
        par[11 * 256 + n] = b21[n];
        par[12 * 256 + n] = b22[n];
    }
    {
        int th = tid & 255;                  // thread index within tile
        if (th < TT) {
            rowf[0][th] = meas[R0h + th];
            rowf[1][th] = event[R0h + th];
            rowf[2][th] = leak[R0h + th];
            rowf[3][th] = elk[R0h + th];
            rowi[0][th] = sids[R0h + th];
            rowi[1][th] = cids[R0h + th];
        }
    }
    __syncthreads();

    // ---- s2: embed (both tiles) ----
    // xr element: row m = rg*16 + 4*q + reg, col n = wh*64 + ntl*16 + c
    float xr[4][4][4];
    #pragma unroll
    for (int rg = 0; rg < 4; ++rg)
        #pragma unroll
        for (int reg = 0; reg < 4; ++reg) {
            int m = rg * 16 + 4 * q + reg;
            float mv = rowf[0][m], ev = rowf[1][m], lv = rowf[2][m], e2 = rowf[3][m];
            const float* srow = stab_table + rowi[0][m] * 256;
            const float* crow = cycle_table + rowi[1][m] * 256;
            #pragma unroll
            for (int ntl = 0; ntl < 4; ++ntl) {
                int n = wh * 64 + ntl * 16 + c;
                xr[rg][ntl][reg] = mv * par[n] + ev * par[256 + n] + lv * par[512 + n]
                                 + e2 * par[768 + n] + par[1024 + n] + srow[n] + crow[n];
            }
        }
    __syncthreads();   // rowf/rowi reads done before redp overlay writes

    float4v acc[4][4];

    auto ln_reduce = [&]() {
        float s[4][4], s2[4][4];
        #pragma unroll
        for (int rg = 0; rg < 4; ++rg)
            #pragma unroll
            for (int reg = 0; reg < 4; ++reg) {
                float a = 0.f, b = 0.f;
                #pragma unroll
                for (int ntl = 0; ntl < 4; ++ntl) {
                    float v = xr[rg][ntl][reg];
                    a += v; b += v * v;
                }
                #pragma unroll
                for (int d = 1; d < 16; d <<= 1) {
                    a += __shfl_xor(a, d, 64);
                    b += __shfl_xor(b, d, 64);
                }
                s[rg][reg] = a; s2[rg][reg] = b;
            }
        if (c == 0) {
            #pragma unroll
            for (int rg = 0; rg < 4; ++rg)
                #pragma unroll
                for (int reg = 0; reg < 4; ++reg) {
                    int m = rg * 16 + 4 * q + reg;
                    redp[m * 12 + wh] = s[rg][reg];
                    redp[m * 12 + 4 + wh] = s2[rg][reg];
                }
        }
    };

    auto ln_write = [&](const float* g, const float* be) {
        float gv[4], bv[4];
        #pragma unroll
        for (int ntl = 0; ntl < 4; ++ntl) {
            int n = wh * 64 + ntl * 16 + c;
            gv[ntl] = g[n]; bv[ntl] = be[n];
        }
        #pragma unroll
        for (int rg = 0; rg < 4; ++rg)
            #pragma unroll
            for (int reg = 0; reg < 4; ++reg) {
                int m = rg * 16 + 4 * q + reg;
                float4v a4 = *(const float4v*)&redp[m * 12];
                float4v b4 = *(const float4v*)&redp[m * 12 + 4];
                float a = a4[0] + a4[1] + a4[2] + a4[3];
                float b = b4[0] + b4[1] + b4[2] + b4[3];
                float mu = a * (1.0f / 256.0f);
                float ve = b * (1.0f / 256.0f) - mu * mu + EPS;
                float rs;
                asm("v_rsq_f32 %0, %1" : "=v"(rs) : "v"(ve));
                #pragma unroll
                for (int ntl = 0; ntl < 4; ++ntl) {
                    int n = wh * 64 + ntl * 16 + c;
                    Ah[aidx(m, n)] = f2bf((xr[rg][ntl][reg] - mu) * rs * gv[ntl] + bv[ntl]);
                }
            }
    };

    short8 bh0[4];
    auto preB = [&](int g4) {
        const short* W = g_Wp + g4 * 65536;
        #pragma unroll
        for (int ntl = 0; ntl < 4; ++ntl) {
            int nt = wh * 4 + ntl;
            bh0[ntl] = *(const short8*)&W[((nt * 8 + 0) * 64 + lane) * 8];
        }
    };

    auto do_gemm = [&](int g4) {
        const short* W = g_Wp + g4 * 65536;
        #pragma unroll
        for (int rg = 0; rg < 4; ++rg)
            #pragma unroll
            for (int ntl = 0; ntl < 4; ++ntl)
                acc[rg][ntl] = (float4v){0.f, 0.f, 0.f, 0.f};
        short8 ah[2][4], bh[2][4];
        #pragma unroll
        for (int rg = 0; rg < 4; ++rg)
            ah[0][rg] = *(const short8*)&Ah[((rg * 8 + 0) * 64 + gl) * 8];
        #pragma unroll
        for (int ntl = 0; ntl < 4; ++ntl)
            bh[0][ntl] = bh0[ntl];
        #pragma unroll
        for (int kb = 0; kb < 8; ++kb) {
            const int cur = kb & 1, nxt = cur ^ 1;
            if (kb < 7) {
                #pragma unroll
                for (int rg = 0; rg < 4; ++rg)
                    ah[nxt][rg] = *(const short8*)&Ah[((rg * 8 + kb + 1) * 64 + gl) * 8];
                #pragma unroll
                for (int ntl = 0; ntl < 4; ++ntl) {
                    int nt = wh * 4 + ntl;
                    bh[nxt][ntl] = *(const short8*)&W[((nt * 8 + kb + 1) * 64 + lane) * 8];
                }
            }
            __builtin_amdgcn_s_setprio(1);
            #pragma unroll
            for (int rg = 0; rg < 4; ++rg)
                #pragma unroll
                for (int ntl = 0; ntl < 4; ++ntl)
                    acc[rg][ntl] = __builtin_amdgcn_mfma_f32_16x16x32_bf16(
                        ah[cur][rg], bh[cur][ntl], acc[rg][ntl], 0, 0, 0);
            __builtin_amdgcn_s_setprio(0);
        }
    };

    auto gelu_write = [&](const float* bias) {
        float bv[4];
        #pragma unroll
        for (int ntl = 0; ntl < 4; ++ntl)
            bv[ntl] = bias[wh * 64 + ntl * 16 + c];
        #pragma unroll
        for (int rg = 0; rg < 4; ++rg)
            #pragma unroll
            for (int ntl = 0; ntl < 4; ++ntl)
                #pragma unroll
                for (int reg = 0; reg < 4; ++reg) {
                    int m = rg * 16 + 4 * q + reg;
                    int n = wh * 64 + ntl * 16 + c;
                    Ah[aidx(m, n)] = f2bf(gelu_erf(acc[rg][ntl][reg] + bv[ntl]));
                }
    };

    auto resadd = [&]() {
        float bv[4];
        #pragma unroll
        for (int ntl = 0; ntl < 4; ++ntl)
            bv[ntl] = par[8 * 256 + wh * 64 + ntl * 16 + c];
        #pragma unroll
        for (int rg = 0; rg < 4; ++rg)
            #pragma unroll
            for (int ntl = 0; ntl < 4; ++ntl)
                #pragma unroll
                for (int reg = 0; reg < 4; ++reg)
                    xr[rg][ntl][reg] += acc[rg][ntl][reg] + bv[ntl];
    };

    auto store_out = [&]() {
        float bv[4];
        #pragma unroll
        for (int ntl = 0; ntl < 4; ++ntl)
            bv[ntl] = par[12 * 256 + wh * 64 + ntl * 16 + c];
        #pragma unroll
        for (int rg = 0; rg < 4; ++rg)
            #pragma unroll
            for (int ntl = 0; ntl < 4; ++ntl)
                #pragma unroll
                for (int reg = 0; reg < 4; ++reg) {
                    int m = rg * 16 + 4 * q + reg;
                    int n = wh * 64 + ntl * 16 + c;
                    out[(size_t)(R0h + m) * 256 + n] =
                        xr[rg][ntl][reg] + acc[rg][ntl][reg] + bv[ntl];
                }
    };

    // ---- anti-phase schedule: tile A (half==0) leads by one sub-phase ----
    // s3
    if (!half) ln_reduce();
    __syncthreads();
    // s4: A:lnwr1  B:lnred1
    if (!half) { preB(0); ln_write(par + 5*256, par + 6*256); } else ln_reduce();
    __syncthreads();
    // s5: A:G1     B:lnwr1
    if (!half) do_gemm(0); else { preB(0); ln_write(par + 5*256, par + 6*256); }
    __syncthreads();
    // s6: A:U1     B:G1
    if (!half) { preB(1); gelu_write(par + 7*256); } else do_gemm(0);
    __syncthreads();
    // s7: A:G2     B:U1
    if (!half) do_gemm(1); else { preB(1); gelu_write(par + 7*256); }
    __syncthreads();
    // s8: A:R      B:G2
    if (!half) resadd(); else do_gemm(1);
    __syncthreads();
    // s9: A:lnred2 B:R
    if (!half) ln_reduce(); else resadd();
    __syncthreads();
    // s10: A:lnwr2 B:lnred2
    if (!half) { preB(2); ln_write(par + 9*256, par + 10*256); } else ln_reduce();
    __syncthreads();
    // s11: A:G3    B:lnwr2
    if (!half) do_gemm(2); else { preB(2); ln_write(par + 9*256, par + 10*256); }
    __syncthreads();
    // s12: A:U2    B:G3
    if (!half) { preB(3); gelu_write(par + 11*256); } else do_gemm(2);
    __syncthreads();
    // s13: A:G4    B:U2
    if (!half) do_gemm(3); else { preB(3); gelu_write(par + 11*256); }
    __syncthreads();
    // s14: A:S     B:G4
    if (!half) store_out(); else do_gemm(3);
    // s15: B:S  (no barrier needed: stores are independent)
    if (half) store_out();
}

extern "C" void kernel_launch(void* const* d_in, const int* in_sizes, int n_in,
                              void* d_out, int out_size, void* d_ws, size_t ws_size,
                              hipStream_t stream) {
    pack_w<<<1024, 256, 0, stream>>>(
        (const float*)d_in[18], (const float*)d_in[20],
        (const float*)d_in[24], (const float*)d_in[26]);
    fused_kernel<<<NTOK / (2 * TT), 512, 0, stream>>>(
        (const float*)d_in[0], (const float*)d_in[1],
        (const float*)d_in[2], (const float*)d_in[3],
        (const int*)d_in[4], (const int*)d_in[5],
        (const float*)d_in[6], (const float*)d_in[8],
        (const float*)d_in[10], (const float*)d_in[12],
        (const float*)d_in[7], (const float*)d_in[9],
        (const float*)d_in[11], (const float*)d_in[13],
        (const float*)d_in[14], (const float*)d_in[15],
        (const float*)d_in[16], (const float*)d_in[17],
        (const float*)d_in[19], (const float*)d_in[21],
        (const float*)d_in[22], (const float*)d_in[23],
        (const float*)d_in[25], (const float*)d_in[27],
        (float*)d_out);
}